// Round 5
// baseline (437.190 us; speedup 1.0000x reference)
//
#include <hip/hip_runtime.h>
#include <hip/hip_bf16.h>

// out[b,o] = sum_i x[b,i] * (W[h,i,o] + 0.1*dW[h*ns+s, i, o])
// IN=10, OUT=8. Counting-sort tokens by head => W/dW locality (80 tok/head,
// dW read in ascending order). All data-derived indices are defensively
// clamped so no input value or atomic race can produce an OOB address
// (rounds 3/4 aborted with a suspected GPU memory fault).
//
// Pipeline (plain 256-thread kernel launches only, graph-capture-safe):
//   zero cnt[NH] -> hist -> 1-block scan(256) -> scatter perm -> compute
// perm entry: {token | split<<24, head}; B=2e6 < 2^24, split < 256.

#define IN_DIM 10
#define OUT_DIM 8

__global__ __launch_bounds__(256) void fd5_zero(unsigned* __restrict__ p, int n)
{
    int i = blockIdx.x * blockDim.x + threadIdx.x;
    const int st = gridDim.x * blockDim.x;
    for (; i < n; i += st) p[i] = 0u;
}

__global__ __launch_bounds__(256) void fd5_hist(
    const int* __restrict__ head_ix, unsigned* __restrict__ cnt, int B, int NH)
{
    int i = blockIdx.x * blockDim.x + threadIdx.x;
    const int st = gridDim.x * blockDim.x;
    for (; i < B; i += st) {
        unsigned h = (unsigned)head_ix[i];
        if (h >= (unsigned)NH) h = 0u;          // defensive clamp
        atomicAdd(&cnt[h], 1u);
    }
}

__global__ __launch_bounds__(256) void fd5_scan(unsigned* __restrict__ cnt, int NH)
{
    __shared__ unsigned ls[256];
    const int tid = threadIdx.x;
    const int chunk = (NH + 255) >> 8;
    const int lo = min(tid * chunk, NH);
    const int hi = min(lo + chunk, NH);
    unsigned s = 0u;
    for (int i = lo; i < hi; ++i) s += cnt[i];
    ls[tid] = s;
    __syncthreads();
    for (int off = 1; off < 256; off <<= 1) {
        unsigned v = (tid >= off) ? ls[tid - off] : 0u;
        __syncthreads();
        ls[tid] += v;
        __syncthreads();
    }
    unsigned run = (tid == 0) ? 0u : ls[tid - 1];   // exclusive base
    for (int i = lo; i < hi; ++i) { unsigned c = cnt[i]; cnt[i] = run; run += c; }
}

__global__ __launch_bounds__(256) void fd5_scatter(
    const int* __restrict__ head_ix, const int* __restrict__ split_ix,
    unsigned* __restrict__ cur, uint2* __restrict__ perm, int B, int NH)
{
    int i = blockIdx.x * blockDim.x + threadIdx.x;
    const int st = gridDim.x * blockDim.x;
    for (; i < B; i += st) {
        unsigned h = (unsigned)head_ix[i];
        if (h >= (unsigned)NH) h = 0u;          // defensive clamp (match hist)
        const unsigned sp = (unsigned)split_ix[i] & 0xFFu;
        const unsigned pos = atomicAdd(&cur[h], 1u);
        if (pos < (unsigned)B)                  // ticket bound: no OOB ever
            perm[pos] = make_uint2((unsigned)i | (sp << 24), h);
    }
}

__global__ __launch_bounds__(256) void fd5_compute(
    const float* __restrict__ x,
    const float* __restrict__ W,
    const float* __restrict__ dW,
    const uint2* __restrict__ perm,
    const int* __restrict__ nsp,
    float* __restrict__ out,
    int B, int NH)
{
    const int gid = blockIdx.x * blockDim.x + threadIdx.x;
    const int p = gid >> 1;          // sorted position
    const int half = gid & 1;        // which half of the 8 outputs
    if (p >= B) return;

    const uint2 e = perm[p];
    int t = (int)(e.x & 0x00FFFFFFu);
    int s = (int)(e.x >> 24);
    int h = (int)e.y;
    int ns = nsp[0];
    if (ns < 1) ns = 1;
    if (t >= B) t = 0;               // defensive
    if (h >= NH) h = 0;              // defensive
    if (s >= ns) s = ns - 1;         // defensive

    const float* __restrict__ wrow = W + (size_t)h * 80 + (size_t)half * 4;
    const float* __restrict__ drow = dW + ((size_t)h * (size_t)ns + (size_t)s) * 80
                                        + (size_t)half * 4;

    const float2* __restrict__ x2 = reinterpret_cast<const float2*>(x + (size_t)t * 10);
    float2 p0 = x2[0], p1 = x2[1], p2 = x2[2], p3 = x2[3], p4 = x2[4];
    const float xv[10] = {p0.x, p0.y, p1.x, p1.y, p2.x, p2.y, p3.x, p3.y, p4.x, p4.y};

    float4 acc = make_float4(0.f, 0.f, 0.f, 0.f);
#pragma unroll
    for (int i = 0; i < 10; ++i) {
        const float4 w4 = *reinterpret_cast<const float4*>(wrow + i * 8);
        const float4 d4 = *reinterpret_cast<const float4*>(drow + i * 8);
        const float xi = xv[i];
        const float xs = 0.1f * xi;
        acc.x = fmaf(xi, w4.x, fmaf(xs, d4.x, acc.x));
        acc.y = fmaf(xi, w4.y, fmaf(xs, d4.y, acc.y));
        acc.z = fmaf(xi, w4.z, fmaf(xs, d4.z, acc.z));
        acc.w = fmaf(xi, w4.w, fmaf(xs, d4.w, acc.w));
    }

    *reinterpret_cast<float4*>(out + (size_t)t * 8 + (size_t)half * 4) = acc;
}

// Fallback (no sort) if the workspace is too small.
__global__ __launch_bounds__(256) void fd5_direct(
    const float* __restrict__ x, const float* __restrict__ W, const float* __restrict__ dW,
    const int* __restrict__ head_ix, const int* __restrict__ split_ix,
    const int* __restrict__ nsp, float* __restrict__ out, int B)
{
    const int gid = blockIdx.x * blockDim.x + threadIdx.x;
    const int t = gid >> 1;
    const int half = gid & 1;
    if (t >= B) return;
    const int ns = nsp[0];
    const int h = head_ix[t];
    const float* wrow = W + (size_t)h * 80 + (size_t)half * 4;
    const float* drow = dW + ((size_t)h * ns + split_ix[t]) * 80 + (size_t)half * 4;
    const float2* x2 = reinterpret_cast<const float2*>(x + (size_t)t * 10);
    float2 p0 = x2[0], p1 = x2[1], p2 = x2[2], p3 = x2[3], p4 = x2[4];
    const float xv[10] = {p0.x, p0.y, p1.x, p1.y, p2.x, p2.y, p3.x, p3.y, p4.x, p4.y};
    float4 acc = make_float4(0.f, 0.f, 0.f, 0.f);
#pragma unroll
    for (int i = 0; i < 10; ++i) {
        const float4 w4 = *reinterpret_cast<const float4*>(wrow + i * 8);
        const float4 d4 = *reinterpret_cast<const float4*>(drow + i * 8);
        const float xi = xv[i], xs = 0.1f * xi;
        acc.x = fmaf(xi, w4.x, fmaf(xs, d4.x, acc.x));
        acc.y = fmaf(xi, w4.y, fmaf(xs, d4.y, acc.y));
        acc.z = fmaf(xi, w4.z, fmaf(xs, d4.z, acc.z));
        acc.w = fmaf(xi, w4.w, fmaf(xs, d4.w, acc.w));
    }
    *reinterpret_cast<float4*>(out + (size_t)t * 8 + (size_t)half * 4) = acc;
}

extern "C" void kernel_launch(void* const* d_in, const int* in_sizes, int n_in,
                              void* d_out, int out_size, void* d_ws, size_t ws_size,
                              hipStream_t stream) {
    const float* x        = (const float*)d_in[0];
    const float* W        = (const float*)d_in[1];
    const float* dW       = (const float*)d_in[2];
    const int*   head_ix  = (const int*)d_in[3];
    const int*   split_ix = (const int*)d_in[4];
    const int*   nsp      = (const int*)d_in[5];
    float* out = (float*)d_out;

    const int B  = in_sizes[0] / IN_DIM;              // x is [B, 10]
    const int NH = in_sizes[1] / (IN_DIM * OUT_DIM);  // W is [NH, 10, 8]

    // workspace layout: cnt/cur [NH] u32 | perm [B] uint2
    const size_t cnt_bytes  = (size_t)NH * sizeof(unsigned);
    const size_t perm_off   = (cnt_bytes + 255) & ~(size_t)255;
    const size_t need_bytes = perm_off + (size_t)B * sizeof(uint2);

    const int block = 256;
    const long long total = 2LL * B;
    const int cgrid = (int)((total + block - 1) / block);

    if (ws_size < need_bytes || d_ws == nullptr || B >= (1 << 24)) {
        fd5_direct<<<cgrid, block, 0, stream>>>(x, W, dW, head_ix, split_ix, nsp, out, B);
        return;
    }

    unsigned* cur = (unsigned*)d_ws;
    uint2* perm   = (uint2*)((char*)d_ws + perm_off);

    const int gs_grid = 2048;  // grid-stride kernels
    fd5_zero<<<(NH + block - 1) / block, block, 0, stream>>>(cur, NH);
    fd5_hist<<<gs_grid, block, 0, stream>>>(head_ix, cur, B, NH);
    fd5_scan<<<1, 256, 0, stream>>>(cur, NH);
    fd5_scatter<<<gs_grid, block, 0, stream>>>(head_ix, split_ix, cur, perm, B, NH);
    fd5_compute<<<cgrid, block, 0, stream>>>(x, W, dW, perm, nsp, out, B, NH);
}

// Round 6
// 129.601 us; speedup vs baseline: 3.3734x; 3.3734x over previous
//
#include <hip/hip_runtime.h>
#include <hip/hip_fp16.h>

// out[b,o] = sum_i x[b,i] * (W[h,i,o] + 0.1*dW[h*ns+s, i, o])
// IN=10, OUT=8.
// Strategy (round 6): NO sort, NO atomics. Precompute combined fp16 table
//   C[g] = fp16(W[g/NS] + 0.1*dW[g]),  g in [0, NH*NS)   -- 64 MB, L3-resident
// Pre-pass is pure streaming (~200 MB). Compute keeps token order: x/idx/out
// are coalesced streams; the only gather is one 160 B fp16 row per token,
// served from Infinity Cache. fp16 weight rounding adds ~5e-3 worst-case
// (threshold 8.4e-2).

#define IN_DIM 10
#define OUT_DIM 8
#define ROW 80  // IN_DIM*OUT_DIM

struct alignas(16) H8 { __half2 a, b, c, d; };

// Build C: thread handles 8 consecutive elements of dW/C.
// j = 8*t; h = j / (80*NS); k = j % 80 (8 | 80 so all 8 elems share h and row).
__global__ __launch_bounds__(256) void fd5_build(
    const float* __restrict__ W, const float* __restrict__ dW,
    __half* __restrict__ C, unsigned total8, unsigned per_head /* 80*NS */)
{
    const unsigned t = blockIdx.x * blockDim.x + threadIdx.x;
    if (t >= total8) return;
    const unsigned j = t * 8u;
    const unsigned h = j / per_head;
    const unsigned k = j % 80u;

    const float4* dw4 = reinterpret_cast<const float4*>(dW + j);
    const float4* w4  = reinterpret_cast<const float4*>(W + (size_t)h * ROW + k);
    const float4 a = dw4[0], b = dw4[1];
    const float4 wa = w4[0], wb = w4[1];

    H8 o;
    o.a = __floats2half2_rn(fmaf(0.1f, a.x, wa.x), fmaf(0.1f, a.y, wa.y));
    o.b = __floats2half2_rn(fmaf(0.1f, a.z, wa.z), fmaf(0.1f, a.w, wa.w));
    o.c = __floats2half2_rn(fmaf(0.1f, b.x, wb.x), fmaf(0.1f, b.y, wb.y));
    o.d = __floats2half2_rn(fmaf(0.1f, b.z, wb.z), fmaf(0.1f, b.w, wb.w));
    *reinterpret_cast<H8*>(C + j) = o;
}

// Compute: 2 lanes per token; lane half=0 -> outputs 0..3, half=1 -> 4..7.
// Per lane: 10x 8B gather from C (L3), coalesced x/idx loads, float4 store.
__global__ __launch_bounds__(256) void fd5_main(
    const float* __restrict__ x, const __half* __restrict__ C,
    const int* __restrict__ head_ix, const int* __restrict__ split_ix,
    float* __restrict__ out, int B, int NS)
{
    const int gid = blockIdx.x * blockDim.x + threadIdx.x;
    const int t = gid >> 1;
    const int hf = gid & 1;
    if (t >= B) return;

    const int h = head_ix[t];
    const int s = split_ix[t];
    const size_t g = (size_t)h * (size_t)NS + (size_t)s;
    const __half* __restrict__ crow = C + g * ROW + (size_t)hf * 4;

    const float2* __restrict__ x2 = reinterpret_cast<const float2*>(x + (size_t)t * 10);
    const float2 p0 = x2[0], p1 = x2[1], p2 = x2[2], p3 = x2[3], p4 = x2[4];
    const float xv[10] = {p0.x, p0.y, p1.x, p1.y, p2.x, p2.y, p3.x, p3.y, p4.x, p4.y};

    float4 acc = make_float4(0.f, 0.f, 0.f, 0.f);
#pragma unroll
    for (int i = 0; i < 10; ++i) {
        const uint2 cu = *reinterpret_cast<const uint2*>(crow + i * 8);
        const __half2 c01 = *reinterpret_cast<const __half2*>(&cu.x);
        const __half2 c23 = *reinterpret_cast<const __half2*>(&cu.y);
        const float2 f01 = __half22float2(c01);
        const float2 f23 = __half22float2(c23);
        const float xi = xv[i];
        acc.x = fmaf(xi, f01.x, acc.x);
        acc.y = fmaf(xi, f01.y, acc.y);
        acc.z = fmaf(xi, f23.x, acc.z);
        acc.w = fmaf(xi, f23.y, acc.w);
    }

    *reinterpret_cast<float4*>(out + (size_t)t * 8 + (size_t)hf * 4) = acc;
}

// Fallback (fp32 direct, round-1 kernel) if workspace can't hold C.
__global__ __launch_bounds__(256) void fd5_direct(
    const float* __restrict__ x, const float* __restrict__ W, const float* __restrict__ dW,
    const int* __restrict__ head_ix, const int* __restrict__ split_ix,
    const int* __restrict__ nsp, float* __restrict__ out, int B)
{
    const int gid = blockIdx.x * blockDim.x + threadIdx.x;
    const int t = gid >> 1;
    const int hf = gid & 1;
    if (t >= B) return;
    const int ns = nsp[0];
    const int h = head_ix[t];
    const float* wrow = W + (size_t)h * ROW + (size_t)hf * 4;
    const float* drow = dW + ((size_t)h * ns + split_ix[t]) * ROW + (size_t)hf * 4;
    const float2* x2 = reinterpret_cast<const float2*>(x + (size_t)t * 10);
    const float2 p0 = x2[0], p1 = x2[1], p2 = x2[2], p3 = x2[3], p4 = x2[4];
    const float xv[10] = {p0.x, p0.y, p1.x, p1.y, p2.x, p2.y, p3.x, p3.y, p4.x, p4.y};
    float4 acc = make_float4(0.f, 0.f, 0.f, 0.f);
#pragma unroll
    for (int i = 0; i < 10; ++i) {
        const float4 w4 = *reinterpret_cast<const float4*>(wrow + i * 8);
        const float4 d4 = *reinterpret_cast<const float4*>(drow + i * 8);
        const float xi = xv[i], xs = 0.1f * xi;
        acc.x = fmaf(xi, w4.x, fmaf(xs, d4.x, acc.x));
        acc.y = fmaf(xi, w4.y, fmaf(xs, d4.y, acc.y));
        acc.z = fmaf(xi, w4.z, fmaf(xs, d4.z, acc.z));
        acc.w = fmaf(xi, w4.w, fmaf(xs, d4.w, acc.w));
    }
    *reinterpret_cast<float4*>(out + (size_t)t * 8 + (size_t)hf * 4) = acc;
}

extern "C" void kernel_launch(void* const* d_in, const int* in_sizes, int n_in,
                              void* d_out, int out_size, void* d_ws, size_t ws_size,
                              hipStream_t stream) {
    const float* x        = (const float*)d_in[0];
    const float* W        = (const float*)d_in[1];
    const float* dW       = (const float*)d_in[2];
    const int*   head_ix  = (const int*)d_in[3];
    const int*   split_ix = (const int*)d_in[4];
    const int*   nsp      = (const int*)d_in[5];
    float* out = (float*)d_out;

    const int B  = in_sizes[0] / IN_DIM;        // x  [B, 10]
    const int NH = in_sizes[1] / ROW;           // W  [NH, 10, 8]
    const int NS = in_sizes[2] / in_sizes[1];   // dW [NH*NS, 10, 8]

    const int block = 256;
    const long long lanes = 2LL * B;
    const int cgrid = (int)((lanes + block - 1) / block);

    const size_t c_elems = (size_t)NH * NS * ROW;            // fp16 elements
    const size_t need    = c_elems * sizeof(__half) + 256;

    if (d_ws == nullptr || ws_size < need) {
        fd5_direct<<<cgrid, block, 0, stream>>>(x, W, dW, head_ix, split_ix, nsp, out, B);
        return;
    }

    __half* C = (__half*)(((uintptr_t)d_ws + 255) & ~(uintptr_t)255);

    const unsigned total8   = (unsigned)(c_elems / 8);       // threads in build
    const unsigned per_head = (unsigned)(ROW * NS);
    const int bgrid = (int)((total8 + block - 1) / block);

    fd5_build<<<bgrid, block, 0, stream>>>(W, dW, C, total8, per_head);
    fd5_main<<<cgrid, block, 0, stream>>>(x, C, head_ix, split_ix, out, B, NS);
}